// Round 1
// 480.536 us; speedup vs baseline: 1.0655x; 1.0655x over previous
//
#include <hip/hip_runtime.h>
#include <hip/hip_bf16.h>

// KronLinear: out = x @ (sum_r kron(a_r, b_r)) + bias
// M=8192 tokens, K=4096=(i,k_b), N=4096=(j,l), RANK=64.
// R3: gemm rewritten as 256x256 tile, BK=32, 8 waves, 4-deep LDS ring with
// counted vmcnt(4) (never 0 in loop) + per-phase barrier/setprio schedule
// (T3+T4+T5 from the 8-phase template). Packed layout unchanged -> prep
// kernel identical; ds_read pattern stays bank-conflict-free (measured 0).

#define M_DIM 8192
#define N_DIM 4096
#define K_DIM 4096
#define KT_COUNT 128   // K_DIM / 32

typedef __attribute__((ext_vector_type(8))) short short8;
typedef __attribute__((ext_vector_type(4))) float floatx4;

typedef __attribute__((address_space(1))) void gvoid_t;
typedef __attribute__((address_space(3))) void lvoid_t;

static __device__ __forceinline__ void gl_lds16(const void* g, const void* l) {
  __builtin_amdgcn_global_load_lds((gvoid_t*)(unsigned long long)g,
                                   (lvoid_t*)(unsigned int)(unsigned long long)l,
                                   16, 0, 0);
}

static __device__ __forceinline__ unsigned short f2bf(float f) {
  unsigned int u = __builtin_bit_cast(unsigned int, f);
  u = (u + 0x7fffu + ((u >> 16) & 1u)) >> 16;  // RNE
  return (unsigned short)u;
}

// ---------------------------------------------------------------------------
// Fused prep: blocks [0,2048) build W^T packed; blocks [2048,10240) pack x.
// build_w first in dispatch order: latency-bound, overlaps pack's BW streaming.
//
// Packed blob (T0, kt) = 128 rows x 32 k: chunk p = c*128 + mm holds
// row (T0*128+mm), k = kt*32 + c*8 .. +7, as 8 bf16 (16B). Identical layout
// for Xp (rows = tokens) and Wp (rows = n = j*64+l).
// ---------------------------------------------------------------------------
__global__ __launch_bounds__(256) void prep_kernel(
    const float* __restrict__ x, const float* __restrict__ a,
    const float* __restrict__ b, unsigned short* __restrict__ Xp,
    unsigned short* __restrict__ Wp) {
  __shared__ float lds[128 * 33];
  const int bid = blockIdx.x;
  const int t = threadIdx.x;

  if (bid < 2048) {
    // ---- build W^T: wT[n=(j*64+l)][i*64+k_b] = sum_r a[r,i,j]*b[r,k_b,l]
    const int rg = bid & 255;
    const int i = rg >> 2;
    const int j0 = (rg & 3) * 16;
    const int k0 = (bid >> 8) * 8;  // 0..56

    {  // stage a[r, i, j0..j0+15] for all r: 1024 floats, [r][16j]
      const int r = t >> 2, jq = t & 3;
      float4 v = ((const float4*)(a + (size_t)r * 4096 + i * 64 + j0))[jq];
      ((float4*)lds)[r * 4 + jq] = v;
    }
    __syncthreads();

    const int l = t & 63;
    const int jj = t >> 6;  // 0..3
    float acc[4][8];
#pragma unroll
    for (int jp = 0; jp < 4; ++jp)
#pragma unroll
      for (int kb = 0; kb < 8; ++kb) acc[jp][kb] = 0.f;

    const float* bb = b + k0 * 64 + l;
#pragma unroll 4
    for (int r = 0; r < 64; ++r) {
      float4 aj = ((const float4*)lds)[r * 4 + jj];
      float bv[8];
#pragma unroll
      for (int kb = 0; kb < 8; ++kb) bv[kb] = bb[(size_t)r * 4096 + kb * 64];
      const float av[4] = {aj.x, aj.y, aj.z, aj.w};
#pragma unroll
      for (int jp = 0; jp < 4; ++jp)
#pragma unroll
        for (int kb = 0; kb < 8; ++kb)
          acc[jp][kb] = fmaf(av[jp], bv[kb], acc[jp][kb]);
    }

    const int kt = (i * 64 + k0) >> 5;
    const int c = (k0 & 31) >> 3;
#pragma unroll
    for (int jp = 0; jp < 4; ++jp) {
      const int j = j0 + jj * 4 + jp;
      const int n = j * 64 + l;
      const int blob = (n >> 7) * KT_COUNT + kt;
      const int pos = c * 128 + (n & 127);
      short8 o;
#pragma unroll
      for (int kb = 0; kb < 8; ++kb) o[kb] = (short)f2bf(acc[jp][kb]);
      *(short8*)(Wp + (size_t)blob * 4096 + pos * 8) = o;
    }
  } else {
    // ---- pack x
    const int pid = bid - 2048;
    const int kt = pid & 127;
    const int M0 = pid >> 7;

    {  // load 128 rows x 32 floats, coalesced (2 threads/row, 64B each)
      const int row = t >> 1;
      const int half = t & 1;
      const float* src = x + (size_t)(M0 * 128 + row) * K_DIM + kt * 32 + half * 16;
      float v[16];
#pragma unroll
      for (int w = 0; w < 4; ++w) {
        float4 vv = ((const float4*)src)[w];
        v[w * 4 + 0] = vv.x; v[w * 4 + 1] = vv.y;
        v[w * 4 + 2] = vv.z; v[w * 4 + 3] = vv.w;
      }
#pragma unroll
      for (int e = 0; e < 16; ++e) lds[row * 33 + half * 16 + e] = v[e];
    }
    __syncthreads();

    unsigned short* dst = Xp + (size_t)(M0 * KT_COUNT + kt) * 4096;
#pragma unroll
    for (int q = 0; q < 2; ++q) {
      const int p = q * 256 + t;
      const int c = p >> 7, mm = p & 127;
      short8 o;
#pragma unroll
      for (int j = 0; j < 8; ++j) o[j] = (short)f2bf(lds[mm * 33 + c * 8 + j]);
      *(short8*)(dst + p * 8) = o;
    }
  }
}

// ---------------------------------------------------------------------------
// GEMM: C = Xp @ Wp^T + bias.  256x256 tile, BK=32, 512 threads (8 waves,
// 2M x 4N), per-wave 128x64 output = acc[8][4] of 16x16 frags.
// LDS: 4-deep ring of K-steps (A 16KB + B 16KB each) = 128 KiB.
// Schedule: 2 phases/K-step, each {ds_read frags || issue 2 gl_lds for t+2;
// barrier; lgkm(0); setprio(1); 16 MFMA; setprio(0); barrier}. Single
// vmcnt(4) per K-step (counted, never 0): allows the 4 freshly-issued t+2
// loads in flight while forcing step t+1 landed before the next iter reads.
// Tail iters issue clamped duplicate loads of step 127 so vmcnt counts stay
// uniform (this is what guarantees step-127 data at kt=126).
// XCD swizzle: bid&7 -> XCD owns 2 N-panels (4MB Wp slice pinned in its L2).
// ---------------------------------------------------------------------------
#define BAR() asm volatile("s_barrier" ::: "memory")
#define WAIT_VM(N) asm volatile("s_waitcnt vmcnt(" #N ")" ::: "memory")
#define WAIT_LGKM0() asm volatile("s_waitcnt lgkmcnt(0)" ::: "memory")

__global__ __launch_bounds__(512, 2) void gemm_kernel(
    const unsigned short* __restrict__ Xp, const unsigned short* __restrict__ Wp,
    const float* __restrict__ bias, float* __restrict__ out) {
  __shared__ short8 As[4][2][512];  // [ring buf][row half][chunk]  64 KiB
  __shared__ short8 Bs[4][2][512];  // [ring buf][col half][chunk]  64 KiB

  const int bid = blockIdx.x;
  const int xcd = bid & 7;
  const int pos = bid >> 3;            // 0..63
  const int N0 = xcd * 2 + (pos & 1);  // 0..15 (256-col panels)
  const int M0 = pos >> 1;             // 0..31 (256-row panels)

  const int t = threadIdx.x;
  const int wave = t >> 6, lane = t & 63;
  const int l16 = lane & 15, quad = lane >> 4;
  const int wm = wave & 1;   // A half (128 rows)
  const int wn = wave >> 1;  // 0..3 (64-col quarter)

  floatx4 acc[8][4];
#pragma unroll
  for (int mt = 0; mt < 8; ++mt)
#pragma unroll
    for (int nt = 0; nt < 4; ++nt) acc[mt][nt] = (floatx4){0.f, 0.f, 0.f, 0.f};

  const unsigned short* gA0 = Xp + (size_t)(M0 * 2 + 0) * KT_COUNT * 4096 + (size_t)t * 8;
  const unsigned short* gA1 = Xp + (size_t)(M0 * 2 + 1) * KT_COUNT * 4096 + (size_t)t * 8;
  const unsigned short* gB0 = Wp + (size_t)(N0 * 2 + 0) * KT_COUNT * 4096 + (size_t)t * 8;
  const unsigned short* gB1 = Wp + (size_t)(N0 * 2 + 1) * KT_COUNT * 4096 + (size_t)t * 8;

  // ---- prologue: stage K-steps 0 and 1 (8 loads), require step 0 landed.
  gl_lds16(gA0, &As[0][0][t]);
  gl_lds16(gA1, &As[0][1][t]);
  gl_lds16(gB0, &Bs[0][0][t]);
  gl_lds16(gB1, &Bs[0][1][t]);
  gl_lds16(gA0 + 4096, &As[1][0][t]);
  gl_lds16(gA1 + 4096, &As[1][1][t]);
  gl_lds16(gB0 + 4096, &Bs[1][0][t]);
  gl_lds16(gB1 + 4096, &Bs[1][1][t]);
  WAIT_VM(4);  // 4 newest (step 1) may stay in flight; step 0 complete
  BAR();

  const int ra = quad * 128 + l16;                  // A chunk base
  const int rb = quad * 128 + (wn & 1) * 64 + l16;  // B chunk base
  const int bh = wn >> 1;                           // B half

#pragma unroll 2
  for (int kt = 0; kt < KT_COUNT; ++kt) {
    const int tb = kt & 3;
    const int db = (kt + 2) & 3;
    const size_t soff =
        (size_t)((kt + 2 < KT_COUNT) ? kt + 2 : KT_COUNT - 1) * 4096;

    short8 bf[4], af[4];

    // ---------------- phase 0: B frags + A rows 0..63, stage A(t+2)
#pragma unroll
    for (int nt = 0; nt < 4; ++nt) bf[nt] = Bs[tb][bh][rb + nt * 16];
#pragma unroll
    for (int m = 0; m < 4; ++m) af[m] = As[tb][wm][ra + m * 16];
    gl_lds16(gA0 + soff, &As[db][0][t]);
    gl_lds16(gA1 + soff, &As[db][1][t]);
    BAR();
    WAIT_LGKM0();
    __builtin_amdgcn_sched_barrier(0);
    __builtin_amdgcn_s_setprio(1);
#pragma unroll
    for (int m = 0; m < 4; ++m)
#pragma unroll
      for (int nt = 0; nt < 4; ++nt)
        acc[m][nt] = __builtin_amdgcn_mfma_f32_16x16x32_bf16(
            af[m], bf[nt], acc[m][nt], 0, 0, 0);
    __builtin_amdgcn_s_setprio(0);
    __builtin_amdgcn_sched_barrier(0);
    BAR();

    // ---------------- phase 1: A rows 64..127, stage B(t+2), counted vmcnt
#pragma unroll
    for (int m = 0; m < 4; ++m) af[m] = As[tb][wm][ra + (4 + m) * 16];
    gl_lds16(gB0 + soff, &Bs[db][0][t]);
    gl_lds16(gB1 + soff, &Bs[db][1][t]);
    WAIT_VM(4);  // allow the 4 t+2 loads in flight; forces step t+1 landed
    BAR();
    WAIT_LGKM0();
    __builtin_amdgcn_sched_barrier(0);
    __builtin_amdgcn_s_setprio(1);
#pragma unroll
    for (int m = 0; m < 4; ++m)
#pragma unroll
      for (int nt = 0; nt < 4; ++nt)
        acc[4 + m][nt] = __builtin_amdgcn_mfma_f32_16x16x32_bf16(
            af[m], bf[nt], acc[4 + m][nt], 0, 0, 0);
    __builtin_amdgcn_s_setprio(0);
    __builtin_amdgcn_sched_barrier(0);
    BAR();
  }

  // ---- epilogue
  const int col_base = N0 * 256 + wn * 64;
  const int row_base = M0 * 256 + wm * 128;
#pragma unroll
  for (int nt = 0; nt < 4; ++nt) {
    const int col = col_base + nt * 16 + l16;
    const float bv = bias[col];
#pragma unroll
    for (int mt = 0; mt < 8; ++mt) {
      floatx4 v = acc[mt][nt];
#pragma unroll
      for (int r4 = 0; r4 < 4; ++r4) {
        const int row = row_base + mt * 16 + quad * 4 + r4;
        out[(size_t)row * N_DIM + col] = v[r4] + bv;
      }
    }
  }
}

extern "C" void kernel_launch(void* const* d_in, const int* in_sizes, int n_in,
                              void* d_out, int out_size, void* d_ws, size_t ws_size,
                              hipStream_t stream) {
  const float* x = (const float*)d_in[0];     // 8192*4096
  const float* a = (const float*)d_in[1];     // 64*64*64 (r,i,j)
  const float* b = (const float*)d_in[2];     // 64*64*64 (r,k,l)
  const float* bias = (const float*)d_in[3];  // 4096
  float* out = (float*)d_out;

  unsigned short* Xp = (unsigned short*)d_ws;        // 67MB
  unsigned short* Wp = Xp + (size_t)M_DIM * K_DIM;   // 33.5MB

  prep_kernel<<<2048 + 8192, 256, 0, stream>>>(x, a, b, Xp, Wp);
  gemm_kernel<<<512, 512, 0, stream>>>(Xp, Wp, bias, out);
}